// Round 5
// baseline (223.794 us; speedup 1.0000x reference)
//
#include <hip/hip_runtime.h>

#define NB_B  2
#define NB_Q  10000
#define NB_D  256
#define NB_NH 8
#define NB_NL 4
#define NB_NP 4
#define NB_HD 32
#define NB_S  21760   // 128*128 + 64*64 + 32*32 + 16*16
#define MQ    20000   // B*Q (divisible by 32)

typedef _Float16 half8 __attribute__((ext_vector_type(8)));
typedef float f32x4 __attribute__((ext_vector_type(4)));

// ---------------------------------------------------------------------------
// Prep: transpose + fp16-convert weights to Wt[n][k] (k-major, 256 k each).
// ---------------------------------------------------------------------------
__global__ __launch_bounds__(256) void k_prepw(const float* __restrict__ Wv,
                                               const float* __restrict__ Ws,
                                               const float* __restrict__ Wa,
                                               const float* __restrict__ Wo,
                                               _Float16* __restrict__ Wvt,
                                               _Float16* __restrict__ Wsat,
                                               _Float16* __restrict__ Wot)
{
    const int k = threadIdx.x;
    const int nc = blockIdx.x;
    if (nc < 256) {
        Wvt[nc * 256 + k] = (_Float16)Wv[k * 256 + nc];
    } else if (nc < 640) {
        const int n = nc - 256;
        const float v = (n < 256) ? Ws[k * 256 + n] : Wa[k * 128 + (n - 256)];
        Wsat[n * 256 + k] = (_Float16)v;
    } else {
        const int n = nc - 640;
        Wot[n * 256 + k] = (_Float16)Wo[k * 256 + n];
    }
}

// ---------------------------------------------------------------------------
// GEMM 1: v = value @ Wv (+bv) -> vt[b][h][s][hd] fp16.
// BM=32, BN=256, BK=32, dbuf LDS, prefetch dist 2. Wave w: cols [w*64,+64).
// ---------------------------------------------------------------------------
__global__ __launch_bounds__(256) void k_vproj_mm(const float* __restrict__ value,
                                                  const _Float16* __restrict__ Wvt,
                                                  const float* __restrict__ bv,
                                                  _Float16* __restrict__ vt)
{
    __shared__ _Float16 Alds[2][32 * 32];    //  4 KB
    __shared__ _Float16 Blds[2][256 * 32];   // 32 KB
    const int t = threadIdx.x;
    const int lane = t & 63, w = t >> 6;
    const int row0 = blockIdx.x * 32;

    const int arow = t & 31, akq = t >> 5;   // A: row, k-quad (4 fp32)
    const float* Ap = value + (size_t)(row0 + arow) * 256 + akq * 4;
    const uint4* Bp = reinterpret_cast<const uint4*>(Wvt + (size_t)t * 256);

    float4 a_n;
    uint4  b_n[4];

    // tile 0 -> lds[0]
    {
        float4 a = *reinterpret_cast<const float4*>(Ap);
        union { uint2 u; _Float16 h[4]; } p;
        p.h[0] = (_Float16)a.x; p.h[1] = (_Float16)a.y; p.h[2] = (_Float16)a.z; p.h[3] = (_Float16)a.w;
        *reinterpret_cast<uint2*>(&Alds[0][((akq >> 1) * 32 + arow) * 8 + (akq & 1) * 4]) = p.u;
#pragma unroll
        for (int i = 0; i < 4; ++i)
            *reinterpret_cast<uint4*>(&Blds[0][(i * 256 + t) * 8]) = Bp[i];
    }
    // tile 1 -> regs
    a_n = *reinterpret_cast<const float4*>(Ap + 32);
#pragma unroll
    for (int i = 0; i < 4; ++i) b_n[i] = Bp[4 + i];
    __syncthreads();

    f32x4 acc[2][4];
#pragma unroll
    for (int fr = 0; fr < 2; ++fr)
#pragma unroll
        for (int fc = 0; fc < 4; ++fc) acc[fr][fc] = (f32x4){0.f, 0.f, 0.f, 0.f};

    for (int kt = 0; kt < 8; ++kt) {
        const int buf = kt & 1;
        half8 af[2], bf[4];
#pragma unroll
        for (int fr = 0; fr < 2; ++fr)
            af[fr] = *reinterpret_cast<const half8*>(&Alds[buf][((lane >> 4) * 32 + fr * 16 + (lane & 15)) * 8]);
#pragma unroll
        for (int fc = 0; fc < 4; ++fc)
            bf[fc] = *reinterpret_cast<const half8*>(&Blds[buf][((lane >> 4) * 256 + w * 64 + fc * 16 + (lane & 15)) * 8]);
#pragma unroll
        for (int fr = 0; fr < 2; ++fr)
#pragma unroll
            for (int fc = 0; fc < 4; ++fc)
                acc[fr][fc] = __builtin_amdgcn_mfma_f32_16x16x32_f16(af[fr], bf[fc], acc[fr][fc], 0, 0, 0);
        if (kt < 7) {
            union { uint2 u; _Float16 h[4]; } p;
            p.h[0] = (_Float16)a_n.x; p.h[1] = (_Float16)a_n.y; p.h[2] = (_Float16)a_n.z; p.h[3] = (_Float16)a_n.w;
            *reinterpret_cast<uint2*>(&Alds[buf ^ 1][((akq >> 1) * 32 + arow) * 8 + (akq & 1) * 4]) = p.u;
#pragma unroll
            for (int i = 0; i < 4; ++i)
                *reinterpret_cast<uint4*>(&Blds[buf ^ 1][(i * 256 + t) * 8]) = b_n[i];
            if (kt < 6) {
                a_n = *reinterpret_cast<const float4*>(Ap + (kt + 2) * 32);
#pragma unroll
                for (int i = 0; i < 4; ++i) b_n[i] = Bp[(kt + 2) * 4 + i];
            }
        }
        __syncthreads();
    }

    const int b = (row0 >= NB_S) ? 1 : 0;
    const int sb = row0 - b * NB_S;
#pragma unroll
    for (int fc = 0; fc < 4; ++fc) {
        const int n = w * 64 + fc * 16 + (lane & 15);
        const int h = n >> 5, hd = n & 31;
        const float bvn = bv[n];
#pragma unroll
        for (int fr = 0; fr < 2; ++fr) {
            const f32x4 c = acc[fr][fc];
#pragma unroll
            for (int j = 0; j < 4; ++j) {
                const int m = fr * 16 + (lane >> 4) * 4 + j;
                vt[((size_t)((b * NB_NH + h) * NB_S + (sb + m)) << 5) + hd] = (_Float16)(c[j] + bvn);
            }
        }
    }
}

// ---------------------------------------------------------------------------
// GEMM 2 (fused): [off|logit] = query @ [Ws|Wa]; epilogue computes pixel
// coords (sx,sy) and softmax weights (sw) directly. BM=32, BN=384.
// ---------------------------------------------------------------------------
__global__ __launch_bounds__(256) void k_coords_mm(const float* __restrict__ query,
                                                   const _Float16* __restrict__ Wsat,
                                                   const float* __restrict__ refp,
                                                   const float* __restrict__ bs,
                                                   const float* __restrict__ ba,
                                                   float* __restrict__ sx,
                                                   float* __restrict__ sy,
                                                   float* __restrict__ sw)
{
    __shared__ _Float16 Alds[2][32 * 32];    //  4 KB
    __shared__ _Float16 Blds[2][384 * 32];   // 48 KB
    __shared__ float rp[32][8];              //  1 KB
    const int t = threadIdx.x;
    const int lane = t & 63, w = t >> 6;
    const int row0 = blockIdx.x * 32;

    const int arow = t & 31, akq = t >> 5;
    const float* Ap = query + (size_t)(row0 + arow) * 256 + akq * 4;

    rp[t >> 3][t & 7] = refp[(size_t)row0 * 8 + t];

    float4 a_n;
    uint4  b_n[6];

    {
        float4 a = *reinterpret_cast<const float4*>(Ap);
        union { uint2 u; _Float16 h[4]; } p;
        p.h[0] = (_Float16)a.x; p.h[1] = (_Float16)a.y; p.h[2] = (_Float16)a.z; p.h[3] = (_Float16)a.w;
        *reinterpret_cast<uint2*>(&Alds[0][((akq >> 1) * 32 + arow) * 8 + (akq & 1) * 4]) = p.u;
#pragma unroll
        for (int i = 0; i < 6; ++i) {
            const int idx = i * 256 + t;
            const int kb = (idx >= 1152) ? 3 : (idx >= 768) ? 2 : (idx >= 384) ? 1 : 0;
            const int n = idx - kb * 384;
            *reinterpret_cast<uint4*>(&Blds[0][idx * 8]) =
                *reinterpret_cast<const uint4*>(Wsat + (size_t)n * 256 + kb * 8);
        }
    }
    a_n = *reinterpret_cast<const float4*>(Ap + 32);
#pragma unroll
    for (int i = 0; i < 6; ++i) {
        const int idx = i * 256 + t;
        const int kb = (idx >= 1152) ? 3 : (idx >= 768) ? 2 : (idx >= 384) ? 1 : 0;
        const int n = idx - kb * 384;
        b_n[i] = *reinterpret_cast<const uint4*>(Wsat + (size_t)n * 256 + 32 + kb * 8);
    }
    __syncthreads();

    f32x4 acc[2][6];
#pragma unroll
    for (int fr = 0; fr < 2; ++fr)
#pragma unroll
        for (int fc = 0; fc < 6; ++fc) acc[fr][fc] = (f32x4){0.f, 0.f, 0.f, 0.f};

    for (int kt = 0; kt < 8; ++kt) {
        const int buf = kt & 1;
        half8 af[2], bf[6];
#pragma unroll
        for (int fr = 0; fr < 2; ++fr)
            af[fr] = *reinterpret_cast<const half8*>(&Alds[buf][((lane >> 4) * 32 + fr * 16 + (lane & 15)) * 8]);
#pragma unroll
        for (int fc = 0; fc < 6; ++fc)
            bf[fc] = *reinterpret_cast<const half8*>(&Blds[buf][((lane >> 4) * 384 + w * 96 + fc * 16 + (lane & 15)) * 8]);
#pragma unroll
        for (int fr = 0; fr < 2; ++fr)
#pragma unroll
            for (int fc = 0; fc < 6; ++fc)
                acc[fr][fc] = __builtin_amdgcn_mfma_f32_16x16x32_f16(af[fr], bf[fc], acc[fr][fc], 0, 0, 0);
        if (kt < 7) {
            union { uint2 u; _Float16 h[4]; } p;
            p.h[0] = (_Float16)a_n.x; p.h[1] = (_Float16)a_n.y; p.h[2] = (_Float16)a_n.z; p.h[3] = (_Float16)a_n.w;
            *reinterpret_cast<uint2*>(&Alds[buf ^ 1][((akq >> 1) * 32 + arow) * 8 + (akq & 1) * 4]) = p.u;
#pragma unroll
            for (int i = 0; i < 6; ++i)
                *reinterpret_cast<uint4*>(&Blds[buf ^ 1][(i * 256 + t) * 8]) = b_n[i];
            if (kt < 6) {
                a_n = *reinterpret_cast<const float4*>(Ap + (kt + 2) * 32);
#pragma unroll
                for (int i = 0; i < 6; ++i) {
                    const int idx = i * 256 + t;
                    const int kb = (idx >= 1152) ? 3 : (idx >= 768) ? 2 : (idx >= 384) ? 1 : 0;
                    const int n = idx - kb * 384;
                    b_n[i] = *reinterpret_cast<const uint4*>(Wsat + (size_t)n * 256 + (kt + 2) * 32 + kb * 8);
                }
            }
        }
        __syncthreads();
    }

    // ---- fused epilogue ----
#pragma unroll
    for (int fc = 0; fc < 6; ++fc) {
        const int nb = w * 96 + fc * 16;
        const int nn = nb + (lane & 15);
        if (nb < 256) {
            // sampling-offset column: nn = ((h*4+l)*4+p)*2+xy
            const int si = nn >> 1, xy = nn & 1;
            const int l = (nn >> 3) & 3;
            const float dim = (float)(128 >> l);
            const float bsv = bs[nn];
            float* dst = xy ? sy : sx;
#pragma unroll
            for (int fr = 0; fr < 2; ++fr) {
                const f32x4 c = acc[fr][fc];
#pragma unroll
                for (int j = 0; j < 4; ++j) {
                    const int m = fr * 16 + (lane >> 4) * 4 + j;
                    const float coord = rp[m][l * 2 + xy] * dim + (c[j] + bsv) - 0.5f;
                    dst[(size_t)(row0 + m) * 128 + si] = coord;
                }
            }
        } else {
            // attention-logit column: col = nn-256 = h*16 + l*4 + p
            const int col = nn - 256;
            const float bav = ba[col];
#pragma unroll
            for (int fr = 0; fr < 2; ++fr) {
                const f32x4 c = acc[fr][fc];
#pragma unroll
                for (int j = 0; j < 4; ++j) {
                    const int m = fr * 16 + (lane >> 4) * 4 + j;
                    float v = c[j] + bav;
                    float vm = v;
                    vm = fmaxf(vm, __shfl_xor(vm, 1));
                    vm = fmaxf(vm, __shfl_xor(vm, 2));
                    vm = fmaxf(vm, __shfl_xor(vm, 4));
                    vm = fmaxf(vm, __shfl_xor(vm, 8));
                    const float e = expf(v - vm);
                    float s = e;
                    s += __shfl_xor(s, 1);
                    s += __shfl_xor(s, 2);
                    s += __shfl_xor(s, 4);
                    s += __shfl_xor(s, 8);
                    sw[(size_t)(row0 + m) * 128 + col] = e / s;
                }
            }
        }
    }
}

// ---------------------------------------------------------------------------
// gather: block = (16 queries, 1 head); head = blockIdx.x & 7 (XCD locality).
// ---------------------------------------------------------------------------
__global__ __launch_bounds__(256) void k_gather(const _Float16* __restrict__ vt,
                                                const float* __restrict__ sx,
                                                const float* __restrict__ sy,
                                                const float* __restrict__ sw,
                                                _Float16* __restrict__ tmp)
{
    __shared__ int   offs[16][16][4];
    __shared__ float wts[16][16][4];
    const int t = threadIdx.x;
    const int gid = blockIdx.x;
    const int h = gid & 7;
    const int row0 = (gid >> 3) * 16;
    const int b = (row0 >= NB_Q) ? 1 : 0;

    {
        const int r = t >> 4, s = t & 15;
        const size_t ci = (size_t)(row0 + r) * 128 + h * 16 + s;
        const float x = sx[ci], y = sy[ci], w = sw[ci];
        const int l = s >> 2;
        const int dim = 128 >> l;
        const int startL = (l == 0) ? 0 : (l == 1) ? 16384 : (l == 2) ? 20480 : 21504;
        const float x0f = floorf(x), y0f = floorf(y);
        const float lx = x - x0f, ly = y - y0f;
        const int ix = (int)x0f, iy = (int)y0f;
        const int ix0 = min(max(ix, 0), dim - 1), ix1 = min(max(ix + 1, 0), dim - 1);
        const int iy0 = min(max(iy, 0), dim - 1), iy1 = min(max(iy + 1, 0), dim - 1);
        const float vx0 = (ix >= 0 && ix < dim) ? 1.f : 0.f;
        const float vx1 = (ix + 1 >= 0 && ix + 1 < dim) ? 1.f : 0.f;
        const float vy0 = (iy >= 0 && iy < dim) ? 1.f : 0.f;
        const float vy1 = (iy + 1 >= 0 && iy + 1 < dim) ? 1.f : 0.f;
        offs[r][s][0] = (startL + iy0 * dim + ix0) * (NB_HD * 2);
        offs[r][s][1] = (startL + iy0 * dim + ix1) * (NB_HD * 2);
        offs[r][s][2] = (startL + iy1 * dim + ix0) * (NB_HD * 2);
        offs[r][s][3] = (startL + iy1 * dim + ix1) * (NB_HD * 2);
        wts[r][s][0] = w * (1.f - lx) * (1.f - ly) * vx0 * vy0;
        wts[r][s][1] = w * lx * (1.f - ly) * vx1 * vy0;
        wts[r][s][2] = w * (1.f - lx) * ly * vx0 * vy1;
        wts[r][s][3] = w * lx * ly * vx1 * vy1;
    }
    __syncthreads();

    const int r = t >> 4, hd2 = t & 15;
    const char* slab = reinterpret_cast<const char*>(vt)
                     + (size_t)(b * NB_NH + h) * NB_S * (NB_HD * 2);
    const int byo = hd2 * 4;
    float ax = 0.f, ay = 0.f;
#pragma unroll
    for (int s = 0; s < 16; ++s) {
        const int4   o = *reinterpret_cast<const int4*>(&offs[r][s][0]);
        const float4 w = *reinterpret_cast<const float4*>(&wts[r][s][0]);
        union { unsigned u; _Float16 h[2]; } c0, c1, c2, c3;
        c0.u = *reinterpret_cast<const unsigned*>(slab + (o.x + byo));
        c1.u = *reinterpret_cast<const unsigned*>(slab + (o.y + byo));
        c2.u = *reinterpret_cast<const unsigned*>(slab + (o.z + byo));
        c3.u = *reinterpret_cast<const unsigned*>(slab + (o.w + byo));
        ax = fmaf(w.x, (float)c0.h[0], ax); ay = fmaf(w.x, (float)c0.h[1], ay);
        ax = fmaf(w.y, (float)c1.h[0], ax); ay = fmaf(w.y, (float)c1.h[1], ay);
        ax = fmaf(w.z, (float)c2.h[0], ax); ay = fmaf(w.z, (float)c2.h[1], ay);
        ax = fmaf(w.w, (float)c3.h[0], ax); ay = fmaf(w.w, (float)c3.h[1], ay);
    }
    union { unsigned u; _Float16 h[2]; } p;
    p.h[0] = (_Float16)ax; p.h[1] = (_Float16)ay;
    *reinterpret_cast<unsigned*>(tmp + (size_t)(row0 + r) * 256 + h * 32 + hd2 * 2) = p.u;
}

// ---------------------------------------------------------------------------
// GEMM 3: out = tmp @ Wo + bo. A fp16. BM=32, BN=256, dbuf.
// ---------------------------------------------------------------------------
__global__ __launch_bounds__(256) void k_oproj_mm(const _Float16* __restrict__ tmp,
                                                  const _Float16* __restrict__ Wot,
                                                  const float* __restrict__ bo,
                                                  float* __restrict__ out)
{
    __shared__ _Float16 Alds[2][32 * 32];
    __shared__ _Float16 Blds[2][256 * 32];
    const int t = threadIdx.x;
    const int lane = t & 63, w = t >> 6;
    const int row0 = blockIdx.x * 32;

    const int arow = t & 31, akq = t >> 5;
    const _Float16* Ap = tmp + (size_t)(row0 + arow) * 256 + akq * 4;
    const uint4* Bp = reinterpret_cast<const uint4*>(Wot + (size_t)t * 256);

    uint2 a_n;
    uint4 b_n[4];

    {
        *reinterpret_cast<uint2*>(&Alds[0][((akq >> 1) * 32 + arow) * 8 + (akq & 1) * 4]) =
            *reinterpret_cast<const uint2*>(Ap);
#pragma unroll
        for (int i = 0; i < 4; ++i)
            *reinterpret_cast<uint4*>(&Blds[0][(i * 256 + t) * 8]) = Bp[i];
    }
    a_n = *reinterpret_cast<const uint2*>(Ap + 32);
#pragma unroll
    for (int i = 0; i < 4; ++i) b_n[i] = Bp[4 + i];
    __syncthreads();

    f32x4 acc[2][4];
#pragma unroll
    for (int fr = 0; fr < 2; ++fr)
#pragma unroll
        for (int fc = 0; fc < 4; ++fc) acc[fr][fc] = (f32x4){0.f, 0.f, 0.f, 0.f};

    for (int kt = 0; kt < 8; ++kt) {
        const int buf = kt & 1;
        half8 af[2], bf[4];
#pragma unroll
        for (int fr = 0; fr < 2; ++fr)
            af[fr] = *reinterpret_cast<const half8*>(&Alds[buf][((lane >> 4) * 32 + fr * 16 + (lane & 15)) * 8]);
#pragma unroll
        for (int fc = 0; fc < 4; ++fc)
            bf[fc] = *reinterpret_cast<const half8*>(&Blds[buf][((lane >> 4) * 256 + w * 64 + fc * 16 + (lane & 15)) * 8]);
#pragma unroll
        for (int fr = 0; fr < 2; ++fr)
#pragma unroll
            for (int fc = 0; fc < 4; ++fc)
                acc[fr][fc] = __builtin_amdgcn_mfma_f32_16x16x32_f16(af[fr], bf[fc], acc[fr][fc], 0, 0, 0);
        if (kt < 7) {
            *reinterpret_cast<uint2*>(&Alds[buf ^ 1][((akq >> 1) * 32 + arow) * 8 + (akq & 1) * 4]) = a_n;
#pragma unroll
            for (int i = 0; i < 4; ++i)
                *reinterpret_cast<uint4*>(&Blds[buf ^ 1][(i * 256 + t) * 8]) = b_n[i];
            if (kt < 6) {
                a_n = *reinterpret_cast<const uint2*>(Ap + (kt + 2) * 32);
#pragma unroll
                for (int i = 0; i < 4; ++i) b_n[i] = Bp[(kt + 2) * 4 + i];
            }
        }
        __syncthreads();
    }

#pragma unroll
    for (int fc = 0; fc < 4; ++fc) {
        const int n = w * 64 + fc * 16 + (lane & 15);
        const float bon = bo[n];
#pragma unroll
        for (int fr = 0; fr < 2; ++fr) {
            const f32x4 c = acc[fr][fc];
#pragma unroll
            for (int j = 0; j < 4; ++j) {
                const int m = fr * 16 + (lane >> 4) * 4 + j;
                out[(size_t)(row0 + m) * 256 + n] = c[j] + bon;
            }
        }
    }
}

// ---------------------------------------------------------------------------
extern "C" void kernel_launch(void* const* d_in, const int* in_sizes, int n_in,
                              void* d_out, int out_size, void* d_ws, size_t ws_size,
                              hipStream_t stream)
{
    const float* query = (const float*)d_in[0];
    const float* refp  = (const float*)d_in[1];
    const float* value = (const float*)d_in[2];
    const float* Wv = (const float*)d_in[4];
    const float* bv = (const float*)d_in[5];
    const float* Ws = (const float*)d_in[6];
    const float* bs = (const float*)d_in[7];
    const float* Wa = (const float*)d_in[8];
    const float* ba = (const float*)d_in[9];
    const float* Wo = (const float*)d_in[10];
    const float* bo = (const float*)d_in[11];
    float* out = (float*)d_out;

    char* ws = (char*)d_ws;
    _Float16* vt_h  = (_Float16*)(ws + 0);          // 43520*256*2   = 22,282,240 B
    _Float16* tmp_h = (_Float16*)(ws + 22282240);   // 20000*256*2   = 10,240,000 B
    _Float16* Wvt   = (_Float16*)(ws + 32522240);   //                   131,072 B
    _Float16* Wsat  = (_Float16*)(ws + 32653312);   //                   196,608 B
    _Float16* Wot   = (_Float16*)(ws + 32849920);   //                   131,072 B
    float*    sxg   = (float*)   (ws + 32980992);   // 20000*128*4   = 10,240,000 B
    float*    syg   = (float*)   (ws + 43220992);
    float*    swg   = (float*)   (ws + 53460992);   // ends 63,700,992

    hipLaunchKernelGGL(k_prepw, dim3(896), dim3(256), 0, stream,
                       Wv, Ws, Wa, Wo, Wvt, Wsat, Wot);
    hipLaunchKernelGGL(k_vproj_mm, dim3(NB_B * NB_S / 32), dim3(256), 0, stream,
                       value, Wvt, bv, vt_h);
    hipLaunchKernelGGL(k_coords_mm, dim3(MQ / 32), dim3(256), 0, stream,
                       query, Wsat, refp, bs, ba, sxg, syg, swg);
    hipLaunchKernelGGL(k_gather, dim3(NB_B * NB_Q / 16 * NB_NH), dim3(256), 0, stream,
                       vt_h, sxg, syg, swg, tmp_h);
    hipLaunchKernelGGL(k_oproj_mm, dim3(MQ / 32), dim3(256), 0, stream,
                       tmp_h, Wot, bo, out);
}

// Round 6
// 131.414 us; speedup vs baseline: 1.7030x; 1.7030x over previous
//
#include <hip/hip_runtime.h>

#define NB_B  2
#define NB_Q  10000
#define NB_D  256
#define NB_NH 8
#define NB_NL 4
#define NB_NP 4
#define NB_HD 32
#define NB_S  21760   // 128*128 + 64*64 + 32*32 + 16*16
#define MQ    20000   // B*Q
#define MQB   313     // ceil(20000/64)

typedef _Float16 half8 __attribute__((ext_vector_type(8)));
typedef float f32x4 __attribute__((ext_vector_type(4)));

// ---------------------------------------------------------------------------
// Prep: transpose + fp16-convert weights to Wt[n][k] (k-major, 256 k each).
// ---------------------------------------------------------------------------
__global__ __launch_bounds__(256) void k_prepw(const float* __restrict__ Wv,
                                               const float* __restrict__ Ws,
                                               const float* __restrict__ Wa,
                                               const float* __restrict__ Wo,
                                               _Float16* __restrict__ Wvt,
                                               _Float16* __restrict__ Wsat,
                                               _Float16* __restrict__ Wot)
{
    const int k = threadIdx.x;
    const int nc = blockIdx.x;
    if (nc < 256) {
        Wvt[nc * 256 + k] = (_Float16)Wv[k * 256 + nc];
    } else if (nc < 640) {
        const int n = nc - 256;
        const float v = (n < 256) ? Ws[k * 256 + n] : Wa[k * 128 + (n - 256)];
        Wsat[n * 256 + k] = (_Float16)v;
    } else {
        const int n = nc - 640;
        Wot[n * 256 + k] = (_Float16)Wo[k * 256 + n];
    }
}

// ---------------------------------------------------------------------------
// GEMM 1: v = value @ Wv (+bv) -> vt[b][h][s][hd] fp16.
// BM=64, BN=128 (2-way N-split), BK=32, sbuf LDS + reg prefetch-1.
// Wave: fr=4 x fc=2 (8 MFMA/K-step). Grid 1360.
// ---------------------------------------------------------------------------
__global__ __launch_bounds__(256) void k_vproj_mm(const float* __restrict__ value,
                                                  const _Float16* __restrict__ Wvt,
                                                  const float* __restrict__ bv,
                                                  _Float16* __restrict__ vt)
{
    __shared__ _Float16 Alds[4 * 64 * 8];    // [kb][row][8k]  4 KB
    __shared__ _Float16 Blds[4 * 128 * 8];   // [kb][nl][8k]   8 KB
    const int t = threadIdx.x;
    const int lane = t & 63, w = t >> 6;
    const int bid = blockIdx.x;
    const int nb = bid & 1;
    const int row0 = (bid >> 1) * 64;
    const int n0 = nb * 128;

    const int srow = t & 63, skq = t >> 6;           // A: row, k-oct
    const float* Ap = value + (size_t)(row0 + srow) * 256 + skq * 8;
    const int nl0 = t & 127, kb0 = t >> 7;           // B: i=0 -> kb0, i=1 -> kb0+2
    const _Float16* Bp0 = Wvt + (size_t)(n0 + nl0) * 256 + kb0 * 8;
    const _Float16* Bp1 = Wvt + (size_t)(n0 + nl0) * 256 + (2 + kb0) * 8;

    float4 a0 = *reinterpret_cast<const float4*>(Ap);
    float4 a1 = *reinterpret_cast<const float4*>(Ap + 4);
    uint4 b0 = *reinterpret_cast<const uint4*>(Bp0);
    uint4 b1 = *reinterpret_cast<const uint4*>(Bp1);

    f32x4 acc[4][2];
#pragma unroll
    for (int fr = 0; fr < 4; ++fr)
#pragma unroll
        for (int fc = 0; fc < 2; ++fc) acc[fr][fc] = (f32x4){0.f, 0.f, 0.f, 0.f};

    for (int kt = 0; kt < 8; ++kt) {
        half8 av;
        av[0] = (_Float16)a0.x; av[1] = (_Float16)a0.y; av[2] = (_Float16)a0.z; av[3] = (_Float16)a0.w;
        av[4] = (_Float16)a1.x; av[5] = (_Float16)a1.y; av[6] = (_Float16)a1.z; av[7] = (_Float16)a1.w;
        *reinterpret_cast<half8*>(&Alds[(skq * 64 + srow) * 8]) = av;
        *reinterpret_cast<uint4*>(&Blds[(kb0 * 128 + nl0) * 8]) = b0;
        *reinterpret_cast<uint4*>(&Blds[((2 + kb0) * 128 + nl0) * 8]) = b1;
        if (kt < 7) {
            const int k0n = (kt + 1) * 32;
            a0 = *reinterpret_cast<const float4*>(Ap + k0n);
            a1 = *reinterpret_cast<const float4*>(Ap + k0n + 4);
            b0 = *reinterpret_cast<const uint4*>(Bp0 + k0n);
            b1 = *reinterpret_cast<const uint4*>(Bp1 + k0n);
        }
        __syncthreads();
        half8 af[4], bf[2];
#pragma unroll
        for (int fr = 0; fr < 4; ++fr)
            af[fr] = *reinterpret_cast<const half8*>(&Alds[((lane >> 4) * 64 + fr * 16 + (lane & 15)) * 8]);
#pragma unroll
        for (int fc = 0; fc < 2; ++fc)
            bf[fc] = *reinterpret_cast<const half8*>(&Blds[((lane >> 4) * 128 + w * 32 + fc * 16 + (lane & 15)) * 8]);
#pragma unroll
        for (int fr = 0; fr < 4; ++fr)
#pragma unroll
            for (int fc = 0; fc < 2; ++fc)
                acc[fr][fc] = __builtin_amdgcn_mfma_f32_16x16x32_f16(af[fr], bf[fc], acc[fr][fc], 0, 0, 0);
        __syncthreads();
    }

    const int b = (row0 >= NB_S) ? 1 : 0;
    const int sb = row0 - b * NB_S;
#pragma unroll
    for (int fc = 0; fc < 2; ++fc) {
        const int n = n0 + w * 32 + fc * 16 + (lane & 15);
        const int h = n >> 5, hd = n & 31;
        const float bvn = bv[n];
#pragma unroll
        for (int fr = 0; fr < 4; ++fr) {
            const f32x4 c = acc[fr][fc];
#pragma unroll
            for (int j = 0; j < 4; ++j) {
                const int m = fr * 16 + (lane >> 4) * 4 + j;
                vt[((size_t)((b * NB_NH + h) * NB_S + (sb + m)) << 5) + hd] = (_Float16)(c[j] + bvn);
            }
        }
    }
}

// ---------------------------------------------------------------------------
// GEMM 2 (fused): query @ [Ws|Wa], 3-way N-split (BN=128). nb=0,1: offsets ->
// pixel coords; nb=2: logits -> softmax weights. Block-uniform epilogue.
// ---------------------------------------------------------------------------
__global__ __launch_bounds__(256) void k_coords_mm(const float* __restrict__ query,
                                                   const _Float16* __restrict__ Wsat,
                                                   const float* __restrict__ refp,
                                                   const float* __restrict__ bs,
                                                   const float* __restrict__ ba,
                                                   float* __restrict__ sx,
                                                   float* __restrict__ sy,
                                                   float* __restrict__ sw)
{
    __shared__ _Float16 Alds[4 * 64 * 8];    //  4 KB
    __shared__ _Float16 Blds[4 * 128 * 8];   //  8 KB
    __shared__ float rp[64][8];              //  2 KB
    const int t = threadIdx.x;
    const int lane = t & 63, w = t >> 6;
    const int bid = blockIdx.x;
    const int nb = bid % 3;
    const int row0 = (bid / 3) * 64;
    const int n0 = nb * 128;

    const int srow = t & 63, skq = t >> 6;
    const bool aok = (row0 + srow) < MQ;
    const float* Ap = query + (size_t)(row0 + srow) * 256 + skq * 8;
    const int nl0 = t & 127, kb0 = t >> 7;
    const _Float16* Bp0 = Wsat + (size_t)(n0 + nl0) * 256 + kb0 * 8;
    const _Float16* Bp1 = Wsat + (size_t)(n0 + nl0) * 256 + (2 + kb0) * 8;

    {
        const int i0 = row0 * 8 + t;
        rp[t >> 3][t & 7] = (i0 < MQ * 8) ? refp[i0] : 0.f;
        const int i1 = i0 + 256;
        rp[32 + (t >> 3)][t & 7] = (i1 < MQ * 8) ? refp[i1] : 0.f;
    }

    float4 a0, a1;
    if (aok) { a0 = *reinterpret_cast<const float4*>(Ap); a1 = *reinterpret_cast<const float4*>(Ap + 4); }
    else     { a0 = float4{0,0,0,0}; a1 = float4{0,0,0,0}; }
    uint4 b0 = *reinterpret_cast<const uint4*>(Bp0);
    uint4 b1 = *reinterpret_cast<const uint4*>(Bp1);

    f32x4 acc[4][2];
#pragma unroll
    for (int fr = 0; fr < 4; ++fr)
#pragma unroll
        for (int fc = 0; fc < 2; ++fc) acc[fr][fc] = (f32x4){0.f, 0.f, 0.f, 0.f};

    for (int kt = 0; kt < 8; ++kt) {
        half8 av;
        av[0] = (_Float16)a0.x; av[1] = (_Float16)a0.y; av[2] = (_Float16)a0.z; av[3] = (_Float16)a0.w;
        av[4] = (_Float16)a1.x; av[5] = (_Float16)a1.y; av[6] = (_Float16)a1.z; av[7] = (_Float16)a1.w;
        *reinterpret_cast<half8*>(&Alds[(skq * 64 + srow) * 8]) = av;
        *reinterpret_cast<uint4*>(&Blds[(kb0 * 128 + nl0) * 8]) = b0;
        *reinterpret_cast<uint4*>(&Blds[((2 + kb0) * 128 + nl0) * 8]) = b1;
        if (kt < 7) {
            const int k0n = (kt + 1) * 32;
            if (aok) { a0 = *reinterpret_cast<const float4*>(Ap + k0n); a1 = *reinterpret_cast<const float4*>(Ap + k0n + 4); }
            b0 = *reinterpret_cast<const uint4*>(Bp0 + k0n);
            b1 = *reinterpret_cast<const uint4*>(Bp1 + k0n);
        }
        __syncthreads();
        half8 af[4], bf[2];
#pragma unroll
        for (int fr = 0; fr < 4; ++fr)
            af[fr] = *reinterpret_cast<const half8*>(&Alds[((lane >> 4) * 64 + fr * 16 + (lane & 15)) * 8]);
#pragma unroll
        for (int fc = 0; fc < 2; ++fc)
            bf[fc] = *reinterpret_cast<const half8*>(&Blds[((lane >> 4) * 128 + w * 32 + fc * 16 + (lane & 15)) * 8]);
#pragma unroll
        for (int fr = 0; fr < 4; ++fr)
#pragma unroll
            for (int fc = 0; fc < 2; ++fc)
                acc[fr][fc] = __builtin_amdgcn_mfma_f32_16x16x32_f16(af[fr], bf[fc], acc[fr][fc], 0, 0, 0);
        __syncthreads();
    }

    if (nb < 2) {
        // sampling-offset columns: n = ((h*4+l)*4+p)*2 + xy
#pragma unroll
        for (int fc = 0; fc < 2; ++fc) {
            const int n = n0 + w * 32 + fc * 16 + (lane & 15);
            const int si = n >> 1, xy = n & 1;
            const int l = (n >> 3) & 3;
            const float dim = (float)(128 >> l);
            const float bsv = bs[n];
            float* dst = xy ? sy : sx;
#pragma unroll
            for (int fr = 0; fr < 4; ++fr) {
                const f32x4 c = acc[fr][fc];
#pragma unroll
                for (int j = 0; j < 4; ++j) {
                    const int m = fr * 16 + (lane >> 4) * 4 + j;
                    if (row0 + m < MQ) {
                        const float coord = rp[m][l * 2 + xy] * dim + (c[j] + bsv) - 0.5f;
                        dst[(size_t)(row0 + m) * 128 + si] = coord;
                    }
                }
            }
        }
    } else {
        // attention-logit columns: col = h*16 + l*4 + p; softmax over 16-lane group
#pragma unroll
        for (int fc = 0; fc < 2; ++fc) {
            const int col = w * 32 + fc * 16 + (lane & 15);
            const float bav = ba[col];
#pragma unroll
            for (int fr = 0; fr < 4; ++fr) {
                const f32x4 c = acc[fr][fc];
#pragma unroll
                for (int j = 0; j < 4; ++j) {
                    const int m = fr * 16 + (lane >> 4) * 4 + j;
                    float v = c[j] + bav;
                    float vm = v;
                    vm = fmaxf(vm, __shfl_xor(vm, 1));
                    vm = fmaxf(vm, __shfl_xor(vm, 2));
                    vm = fmaxf(vm, __shfl_xor(vm, 4));
                    vm = fmaxf(vm, __shfl_xor(vm, 8));
                    const float e = expf(v - vm);
                    float s = e;
                    s += __shfl_xor(s, 1);
                    s += __shfl_xor(s, 2);
                    s += __shfl_xor(s, 4);
                    s += __shfl_xor(s, 8);
                    if (row0 + m < MQ)
                        sw[(size_t)(row0 + m) * 128 + col] = e / s;
                }
            }
        }
    }
}

// ---------------------------------------------------------------------------
// gather: block = (16 queries, 1 head); head = blockIdx.x & 7 (XCD locality).
// ---------------------------------------------------------------------------
__global__ __launch_bounds__(256) void k_gather(const _Float16* __restrict__ vt,
                                                const float* __restrict__ sx,
                                                const float* __restrict__ sy,
                                                const float* __restrict__ sw,
                                                _Float16* __restrict__ tmp)
{
    __shared__ int   offs[16][16][4];
    __shared__ float wts[16][16][4];
    const int t = threadIdx.x;
    const int gid = blockIdx.x;
    const int h = gid & 7;
    const int row0 = (gid >> 3) * 16;
    const int b = (row0 >= NB_Q) ? 1 : 0;

    {
        const int r = t >> 4, s = t & 15;
        const size_t ci = (size_t)(row0 + r) * 128 + h * 16 + s;
        const float x = sx[ci], y = sy[ci], w = sw[ci];
        const int l = s >> 2;
        const int dim = 128 >> l;
        const int startL = (l == 0) ? 0 : (l == 1) ? 16384 : (l == 2) ? 20480 : 21504;
        const float x0f = floorf(x), y0f = floorf(y);
        const float lx = x - x0f, ly = y - y0f;
        const int ix = (int)x0f, iy = (int)y0f;
        const int ix0 = min(max(ix, 0), dim - 1), ix1 = min(max(ix + 1, 0), dim - 1);
        const int iy0 = min(max(iy, 0), dim - 1), iy1 = min(max(iy + 1, 0), dim - 1);
        const float vx0 = (ix >= 0 && ix < dim) ? 1.f : 0.f;
        const float vx1 = (ix + 1 >= 0 && ix + 1 < dim) ? 1.f : 0.f;
        const float vy0 = (iy >= 0 && iy < dim) ? 1.f : 0.f;
        const float vy1 = (iy + 1 >= 0 && iy + 1 < dim) ? 1.f : 0.f;
        offs[r][s][0] = (startL + iy0 * dim + ix0) * (NB_HD * 2);
        offs[r][s][1] = (startL + iy0 * dim + ix1) * (NB_HD * 2);
        offs[r][s][2] = (startL + iy1 * dim + ix0) * (NB_HD * 2);
        offs[r][s][3] = (startL + iy1 * dim + ix1) * (NB_HD * 2);
        wts[r][s][0] = w * (1.f - lx) * (1.f - ly) * vx0 * vy0;
        wts[r][s][1] = w * lx * (1.f - ly) * vx1 * vy0;
        wts[r][s][2] = w * (1.f - lx) * ly * vx0 * vy1;
        wts[r][s][3] = w * lx * ly * vx1 * vy1;
    }
    __syncthreads();

    const int r = t >> 4, hd2 = t & 15;
    const char* slab = reinterpret_cast<const char*>(vt)
                     + (size_t)(b * NB_NH + h) * NB_S * (NB_HD * 2);
    const int byo = hd2 * 4;
    float ax = 0.f, ay = 0.f;
#pragma unroll
    for (int s = 0; s < 16; ++s) {
        const int4   o = *reinterpret_cast<const int4*>(&offs[r][s][0]);
        const float4 w = *reinterpret_cast<const float4*>(&wts[r][s][0]);
        union { unsigned u; _Float16 h[2]; } c0, c1, c2, c3;
        c0.u = *reinterpret_cast<const unsigned*>(slab + (o.x + byo));
        c1.u = *reinterpret_cast<const unsigned*>(slab + (o.y + byo));
        c2.u = *reinterpret_cast<const unsigned*>(slab + (o.z + byo));
        c3.u = *reinterpret_cast<const unsigned*>(slab + (o.w + byo));
        ax = fmaf(w.x, (float)c0.h[0], ax); ay = fmaf(w.x, (float)c0.h[1], ay);
        ax = fmaf(w.y, (float)c1.h[0], ax); ay = fmaf(w.y, (float)c1.h[1], ay);
        ax = fmaf(w.z, (float)c2.h[0], ax); ay = fmaf(w.z, (float)c2.h[1], ay);
        ax = fmaf(w.w, (float)c3.h[0], ax); ay = fmaf(w.w, (float)c3.h[1], ay);
    }
    union { unsigned u; _Float16 h[2]; } p;
    p.h[0] = (_Float16)ax; p.h[1] = (_Float16)ay;
    *reinterpret_cast<unsigned*>(tmp + (size_t)(row0 + r) * 256 + h * 32 + hd2 * 2) = p.u;
}

// ---------------------------------------------------------------------------
// GEMM 3: out = tmp @ Wo + bo. A fp16. BM=64, BN=128 (2-way split). Grid 626.
// ---------------------------------------------------------------------------
__global__ __launch_bounds__(256) void k_oproj_mm(const _Float16* __restrict__ tmp,
                                                  const _Float16* __restrict__ Wot,
                                                  const float* __restrict__ bo,
                                                  float* __restrict__ out)
{
    __shared__ _Float16 Alds[4 * 64 * 8];    //  4 KB
    __shared__ _Float16 Blds[4 * 128 * 8];   //  8 KB
    const int t = threadIdx.x;
    const int lane = t & 63, w = t >> 6;
    const int bid = blockIdx.x;
    const int nb = bid & 1;
    const int row0 = (bid >> 1) * 64;
    const int n0 = nb * 128;

    const int srow = t & 63, skq = t >> 6;
    const bool aok = (row0 + srow) < MQ;
    const _Float16* Ap = tmp + (size_t)(row0 + srow) * 256 + skq * 8;
    const int nl0 = t & 127, kb0 = t >> 7;
    const _Float16* Bp0 = Wot + (size_t)(n0 + nl0) * 256 + kb0 * 8;
    const _Float16* Bp1 = Wot + (size_t)(n0 + nl0) * 256 + (2 + kb0) * 8;

    uint4 a0 = aok ? *reinterpret_cast<const uint4*>(Ap) : uint4{0,0,0,0};
    uint4 b0 = *reinterpret_cast<const uint4*>(Bp0);
    uint4 b1 = *reinterpret_cast<const uint4*>(Bp1);

    f32x4 acc[4][2];
#pragma unroll
    for (int fr = 0; fr < 4; ++fr)
#pragma unroll
        for (int fc = 0; fc < 2; ++fc) acc[fr][fc] = (f32x4){0.f, 0.f, 0.f, 0.f};

    for (int kt = 0; kt < 8; ++kt) {
        *reinterpret_cast<uint4*>(&Alds[(skq * 64 + srow) * 8]) = a0;
        *reinterpret_cast<uint4*>(&Blds[(kb0 * 128 + nl0) * 8]) = b0;
        *reinterpret_cast<uint4*>(&Blds[((2 + kb0) * 128 + nl0) * 8]) = b1;
        if (kt < 7) {
            const int k0n = (kt + 1) * 32;
            if (aok) a0 = *reinterpret_cast<const uint4*>(Ap + k0n);
            b0 = *reinterpret_cast<const uint4*>(Bp0 + k0n);
            b1 = *reinterpret_cast<const uint4*>(Bp1 + k0n);
        }
        __syncthreads();
        half8 af[4], bf[2];
#pragma unroll
        for (int fr = 0; fr < 4; ++fr)
            af[fr] = *reinterpret_cast<const half8*>(&Alds[((lane >> 4) * 64 + fr * 16 + (lane & 15)) * 8]);
#pragma unroll
        for (int fc = 0; fc < 2; ++fc)
            bf[fc] = *reinterpret_cast<const half8*>(&Blds[((lane >> 4) * 128 + w * 32 + fc * 16 + (lane & 15)) * 8]);
#pragma unroll
        for (int fr = 0; fr < 4; ++fr)
#pragma unroll
            for (int fc = 0; fc < 2; ++fc)
                acc[fr][fc] = __builtin_amdgcn_mfma_f32_16x16x32_f16(af[fr], bf[fc], acc[fr][fc], 0, 0, 0);
        __syncthreads();
    }

#pragma unroll
    for (int fc = 0; fc < 2; ++fc) {
        const int n = n0 + w * 32 + fc * 16 + (lane & 15);
        const float bon = bo[n];
#pragma unroll
        for (int fr = 0; fr < 4; ++fr) {
            const f32x4 c = acc[fr][fc];
#pragma unroll
            for (int j = 0; j < 4; ++j) {
                const int m = fr * 16 + (lane >> 4) * 4 + j;
                if (row0 + m < MQ)
                    out[(size_t)(row0 + m) * 256 + n] = c[j] + bon;
            }
        }
    }
}

// ---------------------------------------------------------------------------
extern "C" void kernel_launch(void* const* d_in, const int* in_sizes, int n_in,
                              void* d_out, int out_size, void* d_ws, size_t ws_size,
                              hipStream_t stream)
{
    const float* query = (const float*)d_in[0];
    const float* refp  = (const float*)d_in[1];
    const float* value = (const float*)d_in[2];
    const float* Wv = (const float*)d_in[4];
    const float* bv = (const float*)d_in[5];
    const float* Ws = (const float*)d_in[6];
    const float* bs = (const float*)d_in[7];
    const float* Wa = (const float*)d_in[8];
    const float* ba = (const float*)d_in[9];
    const float* Wo = (const float*)d_in[10];
    const float* bo = (const float*)d_in[11];
    float* out = (float*)d_out;

    char* ws = (char*)d_ws;
    _Float16* vt_h  = (_Float16*)(ws + 0);          // 43520*256*2   = 22,282,240 B
    _Float16* tmp_h = (_Float16*)(ws + 22282240);   // 20000*256*2   = 10,240,000 B
    _Float16* Wvt   = (_Float16*)(ws + 32522240);   //                   131,072 B
    _Float16* Wsat  = (_Float16*)(ws + 32653312);   //                   196,608 B
    _Float16* Wot   = (_Float16*)(ws + 32849920);   //                   131,072 B
    float*    sxg   = (float*)   (ws + 32980992);   // 20000*128*4   = 10,240,000 B
    float*    syg   = (float*)   (ws + 43220992);
    float*    swg   = (float*)   (ws + 53460992);   // ends 63,700,992

    hipLaunchKernelGGL(k_prepw, dim3(896), dim3(256), 0, stream,
                       Wv, Ws, Wa, Wo, Wvt, Wsat, Wot);
    hipLaunchKernelGGL(k_vproj_mm, dim3(NB_B * NB_S / 64 * 2), dim3(256), 0, stream,
                       value, Wvt, bv, vt_h);
    hipLaunchKernelGGL(k_coords_mm, dim3(MQB * 3), dim3(256), 0, stream,
                       query, Wsat, refp, bs, ba, sxg, syg, swg);
    hipLaunchKernelGGL(k_gather, dim3(NB_B * NB_Q / 16 * NB_NH), dim3(256), 0, stream,
                       vt_h, sxg, syg, swg, tmp_h);
    hipLaunchKernelGGL(k_oproj_mm, dim3(MQB * 2), dim3(256), 0, stream,
                       tmp_h, Wot, bo, out);
}

// Round 7
// 123.938 us; speedup vs baseline: 1.8057x; 1.0603x over previous
//
#include <hip/hip_runtime.h>

#define NB_B  2
#define NB_Q  10000
#define NB_D  256
#define NB_NH 8
#define NB_NL 4
#define NB_NP 4
#define NB_HD 32
#define NB_S  21760   // 128*128 + 64*64 + 32*32 + 16*16
#define MQ    20000   // B*Q
#define MQB   313     // ceil(20000/64)
#define NVB   1360    // (B*S/64)*2  vproj blocks
#define NCB   939     // MQB*3       coords blocks

typedef _Float16 half8 __attribute__((ext_vector_type(8)));
typedef float f32x4 __attribute__((ext_vector_type(4)));

// async global->LDS, 16B per lane; lds base must be wave-uniform (HW adds lane*16)
__device__ __forceinline__ void gll16(const void* g, void* l) {
    __builtin_amdgcn_global_load_lds(
        (const __attribute__((address_space(1))) void*)g,
        (__attribute__((address_space(3))) void*)l, 16, 0, 0);
}

// ---------------------------------------------------------------------------
// Prep: transpose + fp16-convert weights to Wt[n][k] (k-major, 256 k each).
// ---------------------------------------------------------------------------
__global__ __launch_bounds__(256) void k_prepw(const float* __restrict__ Wv,
                                               const float* __restrict__ Ws,
                                               const float* __restrict__ Wa,
                                               const float* __restrict__ Wo,
                                               _Float16* __restrict__ Wvt,
                                               _Float16* __restrict__ Wsat,
                                               _Float16* __restrict__ Wot)
{
    const int k = threadIdx.x;
    const int nc = blockIdx.x;
    if (nc < 256) {
        Wvt[nc * 256 + k] = (_Float16)Wv[k * 256 + nc];
    } else if (nc < 640) {
        const int n = nc - 256;
        const float v = (n < 256) ? Ws[k * 256 + n] : Wa[k * 128 + (n - 256)];
        Wsat[n * 256 + k] = (_Float16)v;
    } else {
        const int n = nc - 640;
        Wot[n * 256 + k] = (_Float16)Wo[k * 256 + n];
    }
}

// ---------------------------------------------------------------------------
// k_front: co-launched vproj (blocks [0,NVB)) + coords (blocks [NVB,NVB+NCB)).
// Both: BM=64, BN=128, BK=32, double-buffered LDS, async global_load_lds,
// one barrier per K-step. A staged as fp32 (cvt at fragment read).
// ---------------------------------------------------------------------------
__global__ __launch_bounds__(256) void k_front(const float* __restrict__ value,
                                               const float* __restrict__ query,
                                               const _Float16* __restrict__ Wvt,
                                               const _Float16* __restrict__ Wsat,
                                               const float* __restrict__ refp,
                                               const float* __restrict__ bv,
                                               const float* __restrict__ bs,
                                               const float* __restrict__ ba,
                                               _Float16* __restrict__ vt,
                                               float* __restrict__ sx,
                                               float* __restrict__ sy,
                                               float* __restrict__ sw)
{
    __shared__ float    Af[2][8 * 64 * 4];    // [kq][row][4 f32]  2 x 8 KB
    __shared__ _Float16 Bf[2][4 * 128 * 8];   // [ko][n][8 f16]    2 x 8 KB
    __shared__ float    rp[64][8];            // coords only, 2 KB

    const int t = threadIdx.x;
    const int lane = t & 63, w = t >> 6;
    const int bid = blockIdx.x;
    const bool isv = (bid < NVB);

    int row0, n0;
    const float* Asrc;
    const _Float16* Bsrc;
    if (isv) {
        n0 = (bid & 1) * 128;
        row0 = (bid >> 1) * 64;
        Asrc = value;
        Bsrc = Wvt;
    } else {
        const int cid = bid - NVB;
        n0 = (cid % 3) * 128;
        row0 = (cid / 3) * 64;
        Asrc = query;
        Bsrc = Wsat;
        const int i0 = row0 * 8 + t;
        rp[t >> 3][t & 7] = refp[min(i0, MQ * 8 - 1)];
        const int i1 = i0 + 256;
        rp[32 + (t >> 3)][t & 7] = refp[min(i1, MQ * 8 - 1)];
    }

    const int arow = isv ? (row0 + lane) : min(row0 + lane, MQ - 1);
    const float* ga0 = Asrc + (size_t)arow * 256;
    const _Float16* gb0 = Bsrc + (size_t)(n0 + (w & 1) * 64 + lane) * 256;
    const int ko0 = w >> 1;
    float*    aBase0 = &Af[0][0] ;
    // stage(buf, kt): A kq = {w, w+4}; B ko = {ko0, ko0+2}
    auto stage = [&](int buf, int kt) {
        const float* ga = ga0 + kt * 32;
        gll16(ga + (w    ) * 4, &Af[buf][((w    ) * 64) * 4]);
        gll16(ga + (w + 4) * 4, &Af[buf][((w + 4) * 64) * 4]);
        const _Float16* gb = gb0 + kt * 32;
        gll16(gb + (ko0    ) * 8, &Bf[buf][((ko0    ) * 128 + (w & 1) * 64) * 8]);
        gll16(gb + (ko0 + 2) * 8, &Bf[buf][((ko0 + 2) * 128 + (w & 1) * 64) * 8]);
    };

    f32x4 acc[4][2];
#pragma unroll
    for (int fr = 0; fr < 4; ++fr)
#pragma unroll
        for (int fc = 0; fc < 2; ++fc) acc[fr][fc] = (f32x4){0.f, 0.f, 0.f, 0.f};

    stage(0, 0);
    __syncthreads();

    int buf = 0;
    const int rowb = lane & 15;
    const int kq2 = (lane >> 4) * 2;
    const int ko = lane >> 4;
    for (int kt = 0; kt < 8; ++kt) {
        if (kt < 7) stage(buf ^ 1, kt + 1);
        half8 af[4], bf[2];
#pragma unroll
        for (int fr = 0; fr < 4; ++fr) {
            const float4 f0 = *reinterpret_cast<const float4*>(&Af[buf][(kq2 * 64 + fr * 16 + rowb) * 4]);
            const float4 f1 = *reinterpret_cast<const float4*>(&Af[buf][((kq2 + 1) * 64 + fr * 16 + rowb) * 4]);
            half8 a;
            a[0] = (_Float16)f0.x; a[1] = (_Float16)f0.y; a[2] = (_Float16)f0.z; a[3] = (_Float16)f0.w;
            a[4] = (_Float16)f1.x; a[5] = (_Float16)f1.y; a[6] = (_Float16)f1.z; a[7] = (_Float16)f1.w;
            af[fr] = a;
        }
#pragma unroll
        for (int fc = 0; fc < 2; ++fc)
            bf[fc] = *reinterpret_cast<const half8*>(&Bf[buf][(ko * 128 + w * 32 + fc * 16 + rowb) * 8]);
#pragma unroll
        for (int fr = 0; fr < 4; ++fr)
#pragma unroll
            for (int fc = 0; fc < 2; ++fc)
                acc[fr][fc] = __builtin_amdgcn_mfma_f32_16x16x32_f16(af[fr], bf[fc], acc[fr][fc], 0, 0, 0);
        __syncthreads();
        buf ^= 1;
    }

    if (isv) {
        // ---- vproj epilogue: +bv, store fp16 to vt[b][h][s][hd] ----
        const int b = (row0 >= NB_S) ? 1 : 0;
        const int sb = row0 - b * NB_S;
#pragma unroll
        for (int fc = 0; fc < 2; ++fc) {
            const int n = n0 + w * 32 + fc * 16 + rowb;
            const int h = n >> 5, hd = n & 31;
            const float bvn = bv[n];
#pragma unroll
            for (int fr = 0; fr < 4; ++fr) {
                const f32x4 c = acc[fr][fc];
#pragma unroll
                for (int j = 0; j < 4; ++j) {
                    const int m = fr * 16 + (lane >> 4) * 4 + j;
                    vt[((size_t)((b * NB_NH + h) * NB_S + (sb + m)) << 5) + hd] = (_Float16)(c[j] + bvn);
                }
            }
        }
    } else if (n0 < 256) {
        // ---- coords offsets epilogue: pixel coords ----
#pragma unroll
        for (int fc = 0; fc < 2; ++fc) {
            const int n = n0 + w * 32 + fc * 16 + rowb;
            const int si = n >> 1, xy = n & 1;
            const int l = (n >> 3) & 3;
            const float dim = (float)(128 >> l);
            const float bsv = bs[n];
            float* dst = xy ? sy : sx;
#pragma unroll
            for (int fr = 0; fr < 4; ++fr) {
                const f32x4 c = acc[fr][fc];
#pragma unroll
                for (int j = 0; j < 4; ++j) {
                    const int m = fr * 16 + (lane >> 4) * 4 + j;
                    if (row0 + m < MQ) {
                        const float coord = rp[m][l * 2 + xy] * dim + (c[j] + bsv) - 0.5f;
                        dst[(size_t)(row0 + m) * 128 + si] = coord;
                    }
                }
            }
        }
    } else {
        // ---- coords logits epilogue: softmax over 16-lane group ----
#pragma unroll
        for (int fc = 0; fc < 2; ++fc) {
            const int col = w * 32 + fc * 16 + rowb;
            const float bav = ba[col];
#pragma unroll
            for (int fr = 0; fr < 4; ++fr) {
                const f32x4 c = acc[fr][fc];
#pragma unroll
                for (int j = 0; j < 4; ++j) {
                    const int m = fr * 16 + (lane >> 4) * 4 + j;
                    float v = c[j] + bav;
                    float vm = v;
                    vm = fmaxf(vm, __shfl_xor(vm, 1));
                    vm = fmaxf(vm, __shfl_xor(vm, 2));
                    vm = fmaxf(vm, __shfl_xor(vm, 4));
                    vm = fmaxf(vm, __shfl_xor(vm, 8));
                    const float e = expf(v - vm);
                    float s = e;
                    s += __shfl_xor(s, 1);
                    s += __shfl_xor(s, 2);
                    s += __shfl_xor(s, 4);
                    s += __shfl_xor(s, 8);
                    if (row0 + m < MQ)
                        sw[(size_t)(row0 + m) * 128 + col] = e / s;
                }
            }
        }
    }
    (void)aBase0;
}

// ---------------------------------------------------------------------------
// gather: block = (16 queries, 1 head); head = blockIdx.x & 7 (XCD locality).
// ---------------------------------------------------------------------------
__global__ __launch_bounds__(256) void k_gather(const _Float16* __restrict__ vt,
                                                const float* __restrict__ sx,
                                                const float* __restrict__ sy,
                                                const float* __restrict__ sw,
                                                _Float16* __restrict__ tmp)
{
    __shared__ int   offs[16][16][4];
    __shared__ float wts[16][16][4];
    const int t = threadIdx.x;
    const int gid = blockIdx.x;
    const int h = gid & 7;
    const int row0 = (gid >> 3) * 16;
    const int b = (row0 >= NB_Q) ? 1 : 0;

    {
        const int r = t >> 4, s = t & 15;
        const size_t ci = (size_t)(row0 + r) * 128 + h * 16 + s;
        const float x = sx[ci], y = sy[ci], w = sw[ci];
        const int l = s >> 2;
        const int dim = 128 >> l;
        const int startL = (l == 0) ? 0 : (l == 1) ? 16384 : (l == 2) ? 20480 : 21504;
        const float x0f = floorf(x), y0f = floorf(y);
        const float lx = x - x0f, ly = y - y0f;
        const int ix = (int)x0f, iy = (int)y0f;
        const int ix0 = min(max(ix, 0), dim - 1), ix1 = min(max(ix + 1, 0), dim - 1);
        const int iy0 = min(max(iy, 0), dim - 1), iy1 = min(max(iy + 1, 0), dim - 1);
        const float vx0 = (ix >= 0 && ix < dim) ? 1.f : 0.f;
        const float vx1 = (ix + 1 >= 0 && ix + 1 < dim) ? 1.f : 0.f;
        const float vy0 = (iy >= 0 && iy < dim) ? 1.f : 0.f;
        const float vy1 = (iy + 1 >= 0 && iy + 1 < dim) ? 1.f : 0.f;
        offs[r][s][0] = (startL + iy0 * dim + ix0) * (NB_HD * 2);
        offs[r][s][1] = (startL + iy0 * dim + ix1) * (NB_HD * 2);
        offs[r][s][2] = (startL + iy1 * dim + ix0) * (NB_HD * 2);
        offs[r][s][3] = (startL + iy1 * dim + ix1) * (NB_HD * 2);
        wts[r][s][0] = w * (1.f - lx) * (1.f - ly) * vx0 * vy0;
        wts[r][s][1] = w * lx * (1.f - ly) * vx1 * vy0;
        wts[r][s][2] = w * (1.f - lx) * ly * vx0 * vy1;
        wts[r][s][3] = w * lx * ly * vx1 * vy1;
    }
    __syncthreads();

    const int r = t >> 4, hd2 = t & 15;
    const char* slab = reinterpret_cast<const char*>(vt)
                     + (size_t)(b * NB_NH + h) * NB_S * (NB_HD * 2);
    const int byo = hd2 * 4;
    float ax = 0.f, ay = 0.f;
#pragma unroll
    for (int s = 0; s < 16; ++s) {
        const int4   o = *reinterpret_cast<const int4*>(&offs[r][s][0]);
        const float4 w = *reinterpret_cast<const float4*>(&wts[r][s][0]);
        union { unsigned u; _Float16 h[2]; } c0, c1, c2, c3;
        c0.u = *reinterpret_cast<const unsigned*>(slab + (o.x + byo));
        c1.u = *reinterpret_cast<const unsigned*>(slab + (o.y + byo));
        c2.u = *reinterpret_cast<const unsigned*>(slab + (o.z + byo));
        c3.u = *reinterpret_cast<const unsigned*>(slab + (o.w + byo));
        ax = fmaf(w.x, (float)c0.h[0], ax); ay = fmaf(w.x, (float)c0.h[1], ay);
        ax = fmaf(w.y, (float)c1.h[0], ax); ay = fmaf(w.y, (float)c1.h[1], ay);
        ax = fmaf(w.z, (float)c2.h[0], ax); ay = fmaf(w.z, (float)c2.h[1], ay);
        ax = fmaf(w.w, (float)c3.h[0], ax); ay = fmaf(w.w, (float)c3.h[1], ay);
    }
    union { unsigned u; _Float16 h[2]; } p;
    p.h[0] = (_Float16)ax; p.h[1] = (_Float16)ay;
    *reinterpret_cast<unsigned*>(tmp + (size_t)(row0 + r) * 256 + h * 32 + hd2 * 2) = p.u;
}

// ---------------------------------------------------------------------------
// oproj: out = tmp @ Wo + bo. BM=64, BN=128 (2-way), BK=32, dbuf + async.
// ---------------------------------------------------------------------------
__global__ __launch_bounds__(256) void k_oproj_mm(const _Float16* __restrict__ tmp,
                                                  const _Float16* __restrict__ Wot,
                                                  const float* __restrict__ bo,
                                                  float* __restrict__ out)
{
    __shared__ _Float16 Ao[2][4 * 64 * 8];    // [ko][row][8 f16]  2 x 4 KB
    __shared__ _Float16 Bf[2][4 * 128 * 8];   //                   2 x 8 KB
    const int t = threadIdx.x;
    const int lane = t & 63, w = t >> 6;
    const int bid = blockIdx.x;
    const int n0 = (bid & 1) * 128;
    const int row0 = (bid >> 1) * 64;

    const int arow = min(row0 + lane, MQ - 1);
    const _Float16* ga0 = tmp + (size_t)arow * 256;
    const _Float16* gb0 = Wot + (size_t)(n0 + (w & 1) * 64 + lane) * 256;
    const int ko0 = w >> 1;
    auto stage = [&](int buf, int kt) {
        gll16(ga0 + kt * 32 + w * 8, &Ao[buf][(w * 64) * 8]);
        const _Float16* gb = gb0 + kt * 32;
        gll16(gb + (ko0    ) * 8, &Bf[buf][((ko0    ) * 128 + (w & 1) * 64) * 8]);
        gll16(gb + (ko0 + 2) * 8, &Bf[buf][((ko0 + 2) * 128 + (w & 1) * 64) * 8]);
    };

    f32x4 acc[4][2];
#pragma unroll
    for (int fr = 0; fr < 4; ++fr)
#pragma unroll
        for (int fc = 0; fc < 2; ++fc) acc[fr][fc] = (f32x4){0.f, 0.f, 0.f, 0.f};

    stage(0, 0);
    __syncthreads();

    int buf = 0;
    const int rowb = lane & 15;
    const int ko = lane >> 4;
    for (int kt = 0; kt < 8; ++kt) {
        if (kt < 7) stage(buf ^ 1, kt + 1);
        half8 af[4], bf[2];
#pragma unroll
        for (int fr = 0; fr < 4; ++fr)
            af[fr] = *reinterpret_cast<const half8*>(&Ao[buf][(ko * 64 + fr * 16 + rowb) * 8]);
#pragma unroll
        for (int fc = 0; fc < 2; ++fc)
            bf[fc] = *reinterpret_cast<const half8*>(&Bf[buf][(ko * 128 + w * 32 + fc * 16 + rowb) * 8]);
#pragma unroll
        for (int fr = 0; fr < 4; ++fr)
#pragma unroll
            for (int fc = 0; fc < 2; ++fc)
                acc[fr][fc] = __builtin_amdgcn_mfma_f32_16x16x32_f16(af[fr], bf[fc], acc[fr][fc], 0, 0, 0);
        __syncthreads();
        buf ^= 1;
    }

#pragma unroll
    for (int fc = 0; fc < 2; ++fc) {
        const int n = n0 + w * 32 + fc * 16 + rowb;
        const float bon = bo[n];
#pragma unroll
        for (int fr = 0; fr < 4; ++fr) {
            const f32x4 c = acc[fr][fc];
#pragma unroll
            for (int j = 0; j < 4; ++j) {
                const int m = fr * 16 + (lane >> 4) * 4 + j;
                if (row0 + m < MQ)
                    out[(size_t)(row0 + m) * 256 + n] = c[j] + bon;
            }
        }
    }
}

// ---------------------------------------------------------------------------
extern "C" void kernel_launch(void* const* d_in, const int* in_sizes, int n_in,
                              void* d_out, int out_size, void* d_ws, size_t ws_size,
                              hipStream_t stream)
{
    const float* query = (const float*)d_in[0];
    const float* refp  = (const float*)d_in[1];
    const float* value = (const float*)d_in[2];
    const float* Wv = (const float*)d_in[4];
    const float* bv = (const float*)d_in[5];
    const float* Ws = (const float*)d_in[6];
    const float* bs = (const float*)d_in[7];
    const float* Wa = (const float*)d_in[8];
    const float* ba = (const float*)d_in[9];
    const float* Wo = (const float*)d_in[10];
    const float* bo = (const float*)d_in[11];
    float* out = (float*)d_out;

    char* ws = (char*)d_ws;
    _Float16* vt_h  = (_Float16*)(ws + 0);          // 43520*256*2   = 22,282,240 B
    _Float16* tmp_h = (_Float16*)(ws + 22282240);   // 20000*256*2   = 10,240,000 B
    _Float16* Wvt   = (_Float16*)(ws + 32522240);   //                   131,072 B
    _Float16* Wsat  = (_Float16*)(ws + 32653312);   //                   196,608 B
    _Float16* Wot   = (_Float16*)(ws + 32849920);   //                   131,072 B
    float*    sxg   = (float*)   (ws + 32980992);   // 20000*128*4   = 10,240,000 B
    float*    syg   = (float*)   (ws + 43220992);
    float*    swg   = (float*)   (ws + 53460992);   // ends 63,700,992

    hipLaunchKernelGGL(k_prepw, dim3(896), dim3(256), 0, stream,
                       Wv, Ws, Wa, Wo, Wvt, Wsat, Wot);
    hipLaunchKernelGGL(k_front, dim3(NVB + NCB), dim3(256), 0, stream,
                       value, query, Wvt, Wsat, refp, bv, bs, ba,
                       vt_h, sxg, syg, swg);
    hipLaunchKernelGGL(k_gather, dim3(NB_B * NB_Q / 16 * NB_NH), dim3(256), 0, stream,
                       vt_h, sxg, syg, swg, tmp_h);
    hipLaunchKernelGGL(k_oproj_mm, dim3(MQB * 2), dim3(256), 0, stream,
                       tmp_h, Wot, bo, out);
}